// Round 1
// 216.278 us; speedup vs baseline: 1.0437x; 1.0437x over previous
//
#include <hip/hip_runtime.h>
#include <math.h>

// Problem constants
#define NN 8
#define C_TOTAL 448
#define CC 100
#define HH 56
#define WW 56
#define HW (HH*WW)          // 3136
#define NPIX4 (HW/4)        // 784 quads (float4 pixel groups)
#define OH 224
#define OW 224
#define NT4 13              // ceil(784/64) quad tiles
#define NK 50               // adjacent-row pairs: block k handles rows (2k, 2k+1)

typedef __attribute__((ext_vector_type(4))) _Float16 half4;
typedef __attribute__((ext_vector_type(8))) _Float16 half8;

__device__ __forceinline__ void fma4(float4& acc, const float4 a, const float4 b) {
    acc.x = fmaf(a.x, b.x, acc.x);
    acc.y = fmaf(a.y, b.y, acc.y);
    acc.z = fmaf(a.z, b.z, acc.z);
    acc.w = fmaf(a.w, b.w, acc.w);
}
__device__ __forceinline__ float4 h2f(const half4 h) {
    float4 r; r.x = (float)h.x; r.y = (float)h.y; r.z = (float)h.z; r.w = (float)h.w;
    return r;
}

// ---------------------------------------------------------------------------
// Kernel 0: x -> fp16, TRANSPOSED layout xbuf[c][quad][n] (half4 elements).
// One thread per (c, quad); loops n internally; writes one contiguous 64 B run.
// Also zeroes the smap accumulator (first NN*NPIX4 threads).
// ---------------------------------------------------------------------------
__global__ __launch_bounds__(256) void prep_x_kernel(
    const float* __restrict__ fmaps, const int* __restrict__ sel,
    const float* __restrict__ mean, half4* __restrict__ xbuf,
    float* __restrict__ smap)
{
    const int idx = blockIdx.x * 256 + threadIdx.x;
    if (idx < NN * NPIX4) {
        ((float4*)smap)[idx] = make_float4(0.f, 0.f, 0.f, 0.f);
    }
    if (idx >= CC * NPIX4) return;
    const int quad = idx % NPIX4;
    const int c    = idx / NPIX4;

    const float4* f4 = (const float4*)fmaps;
    const float4  m  = ((const float4*)mean)[(size_t)c * NPIX4 + quad];
    const int     sc = sel[c];

    half4 hv[NN];
#pragma unroll
    for (int n = 0; n < NN; ++n) {
        const float4 f = f4[((size_t)n * C_TOTAL + sc) * NPIX4 + quad];
        half4 h;
        h.x = (_Float16)(f.x - m.x);
        h.y = (_Float16)(f.y - m.y);
        h.z = (_Float16)(f.z - m.z);
        h.w = (_Float16)(f.w - m.w);
        hv[n] = h;
    }
    half4* dst = xbuf + ((size_t)c * NPIX4 + quad) * NN;   // 64 B contiguous
#pragma unroll
    for (int n = 0; n < NN; ++n) dst[n] = hv[n];
}

// ---------------------------------------------------------------------------
// Kernel 1: adjacent-row pair (a=2k, b=2k+1), single joint d-loop:
//   one x[d] load (+one fp16->fp32 convert) feeds FMAs for BOTH cov rows.
//   Upper-triangle symmetry: acc_row = sum_{d>=row} w_d cov[row,d] x_d,
//   diag weight 0.5; contribution = 2*(x_a.acc_a + x_b.acc_b).
//   Cross-wave sum via 64 KB LDS dump + barrier, then atomicAdd into smap.
//   Blocks ordered k-ascending -> longest blocks dispatch first (clean tail).
// ---------------------------------------------------------------------------
__global__ __launch_bounds__(512, 4) void qform_kernel(
    const half4* __restrict__ xbuf, const float* __restrict__ cov,
    float* __restrict__ smap)
{
    __shared__ float4 lred[NN * NN * 64];   // [wave][n][lane] = 64 KB

    const int tile = blockIdx.x % NT4;
    const int k    = blockIdx.x / NT4;      // 0..49
    const int a    = 2 * k;
    const int b    = a + 1;
    const int w    = threadIdx.x >> 6;      // wave id 0..7
    const int lane = threadIdx.x & 63;
    const int qraw = tile * 64 + lane;
    const bool valid = qraw < NPIX4;
    const int quad = valid ? qraw : (NPIX4 - 1);   // clamp, no early return

    const float4* c4 = (const float4*)cov;

    float4 acca[NN], accb[NN];
#pragma unroll
    for (int n = 0; n < NN; ++n) {
        acca[n] = make_float4(0.f, 0.f, 0.f, 0.f);
        accb[n] = make_float4(0.f, 0.f, 0.f, 0.f);
    }

    // cols d = a + w, step 8 (wave-uniform trip count)
    for (int d = a + w; d < CC; d += NN) {
        const half8* xp = (const half8*)(xbuf + ((size_t)d * NPIX4 + quad) * NN);
        const half8 p0 = xp[0];
        const half8 p1 = xp[1];
        const half8 p2 = xp[2];
        const half8 p3 = xp[3];
        float4 xv[NN];
        xv[0] = make_float4((float)p0[0], (float)p0[1], (float)p0[2], (float)p0[3]);
        xv[1] = make_float4((float)p0[4], (float)p0[5], (float)p0[6], (float)p0[7]);
        xv[2] = make_float4((float)p1[0], (float)p1[1], (float)p1[2], (float)p1[3]);
        xv[3] = make_float4((float)p1[4], (float)p1[5], (float)p1[6], (float)p1[7]);
        xv[4] = make_float4((float)p2[0], (float)p2[1], (float)p2[2], (float)p2[3]);
        xv[5] = make_float4((float)p2[4], (float)p2[5], (float)p2[6], (float)p2[7]);
        xv[6] = make_float4((float)p3[0], (float)p3[1], (float)p3[2], (float)p3[3]);
        xv[7] = make_float4((float)p3[4], (float)p3[5], (float)p3[6], (float)p3[7]);

        float4 cva = c4[((size_t)a * CC + d) * NPIX4 + quad];
        if (d == a) { cva.x *= 0.5f; cva.y *= 0.5f; cva.z *= 0.5f; cva.w *= 0.5f; }
#pragma unroll
        for (int n = 0; n < NN; ++n) fma4(acca[n], xv[n], cva);

        if (d > a) {        // d >= b (wave-uniform branch; false only for w==0, j==0)
            float4 cvb = c4[((size_t)b * CC + d) * NPIX4 + quad];
            if (d == b) { cvb.x *= 0.5f; cvb.y *= 0.5f; cvb.z *= 0.5f; cvb.w *= 0.5f; }
#pragma unroll
            for (int n = 0; n < NN; ++n) fma4(accb[n], xv[n], cvb);
        }
    }

    // fold: part[n] = 2*(x_a[n]*acc_a[n] + x_b[n]*acc_b[n]); dump to LDS
    const half4* xap = xbuf + ((size_t)a * NPIX4 + quad) * NN;
    const half4* xbp = xbuf + ((size_t)b * NPIX4 + quad) * NN;
#pragma unroll
    for (int n = 0; n < NN; ++n) {
        const float4 xa = h2f(xap[n]);
        const float4 xb = h2f(xbp[n]);
        float4 t;
        t.x = 2.f * fmaf(xb.x, accb[n].x, xa.x * acca[n].x);
        t.y = 2.f * fmaf(xb.y, accb[n].y, xa.y * acca[n].y);
        t.z = 2.f * fmaf(xb.z, accb[n].z, xa.z * acca[n].z);
        t.w = 2.f * fmaf(xb.w, accb[n].w, xa.w * acca[n].w);
        lred[(w * NN + n) * 64 + lane] = t;
    }
    __syncthreads();

    {
        const int n = w;   // wave w reduces image n
        float4 sum = make_float4(0.f, 0.f, 0.f, 0.f);
#pragma unroll
        for (int ww = 0; ww < NN; ++ww) {
            const float4 v = lred[(ww * NN + n) * 64 + lane];
            sum.x += v.x; sum.y += v.y; sum.z += v.z; sum.w += v.w;
        }
        if (valid) {
            float* dst = smap + (size_t)n * HW + (size_t)qraw * 4;
            atomicAdd(dst + 0, sum.x);
            atomicAdd(dst + 1, sum.y);
            atomicAdd(dst + 2, sum.z);
            atomicAdd(dst + 3, sum.w);
        }
    }
}

// ---------------------------------------------------------------------------
// Kernel 2: sqrt + bilinear x4 upsample (half-pixel, edge clamp) + normalize
// ---------------------------------------------------------------------------
__global__ __launch_bounds__(256) void upsample_kernel(
    const float* __restrict__ smap,
    const float* __restrict__ minp, const float* __restrict__ maxp,
    float* __restrict__ out)
{
    const int idx = blockIdx.x * 256 + threadIdx.x;
    const int total = NN * OH * OW;
    if (idx >= total) return;

    const int ox = idx % OW;
    const int oy = (idx / OW) % OH;
    const int n  = idx / (OW * OH);

    const float fy = oy * 0.25f - 0.375f;
    const float fx = ox * 0.25f - 0.375f;

    int y0 = (int)floorf(fy);
    int x0 = (int)floorf(fx);
    const float wy = fy - (float)y0;
    const float wx = fx - (float)x0;
    int y1 = min(y0 + 1, HH - 1); y0 = max(y0, 0);
    int x1 = min(x0 + 1, WW - 1); x0 = max(x0, 0);

    const float* s = smap + (size_t)n * HW;
    const float v00 = sqrtf(fmaxf(s[y0 * WW + x0], 0.f));
    const float v01 = sqrtf(fmaxf(s[y0 * WW + x1], 0.f));
    const float v10 = sqrtf(fmaxf(s[y1 * WW + x0], 0.f));
    const float v11 = sqrtf(fmaxf(s[y1 * WW + x1], 0.f));

    const float v = (1.0f - wy) * ((1.0f - wx) * v00 + wx * v01)
                  +          wy * ((1.0f - wx) * v10 + wx * v11);

    const float mn = *minp;
    const float mx = *maxp;
    out[idx] = (v - mn) / (mx - mn);
}

// ---------------------------------------------------------------------------
extern "C" void kernel_launch(void* const* d_in, const int* in_sizes, int n_in,
                              void* d_out, int out_size, void* d_ws, size_t ws_size,
                              hipStream_t stream)
{
    const float* fmaps = (const float*)d_in[0];
    const int*   sel   = (const int*)  d_in[1];
    const float* mean  = (const float*)d_in[2];
    const float* cov   = (const float*)d_in[3];
    const float* minp  = (const float*)d_in[4];
    const float* maxp  = (const float*)d_in[5];
    float* out = (float*)d_out;

    half4* xbuf = (half4*)d_ws;                                   // CC*NPIX4*NN half4 = 5.0 MB
    float* smap = (float*)((char*)d_ws + (size_t)CC*NPIX4*NN*8);  // NN*HW f32 = 0.1 MB (atomic acc)

    {
        const int total = CC * NPIX4;
        prep_x_kernel<<<(total + 255) / 256, 256, 0, stream>>>(fmaps, sel, mean, xbuf, smap);
    }
    qform_kernel<<<NT4 * NK, 512, 0, stream>>>(xbuf, cov, smap);
    {
        const int total = NN * OH * OW;
        upsample_kernel<<<(total + 255) / 256, 256, 0, stream>>>(smap, minp, maxp, out);
    }
}